// Round 9
// baseline (1510.370 us; speedup 1.0000x reference)
//
#include <hip/hip_runtime.h>

typedef float v4f __attribute__((ext_vector_type(4)));

#define HID 30
#define TSTEPS 2048
#define BATCH 512
#define RING 64
#define L2E 1.4426950408889634f

__device__ __forceinline__ float fexp2(float x) { return __builtin_amdgcn_exp2f(x); }
__device__ __forceinline__ float frcp(float x)  { return __builtin_amdgcn_rcpf(x); }
__device__ __forceinline__ void  pinf(float& v) { asm("" : "+v"(v)); }

// broadcast lane l of v to all lanes — VALU, result lands in SGPR
__device__ __forceinline__ float rl(float v, int l) {
    return __int_as_float(__builtin_amdgcn_readlane(__float_as_int(v), l));
}

// p from the other 32-lane half (lane ^ 32) via gfx950 VALU permlane32_swap.
//   ret0 = {p.row0,p.row0} -> what h=1 lanes need; ret1 -> what h=0 lanes need.
__device__ __forceinline__ float other_half(float p, int h) {
#if __has_builtin(__builtin_amdgcn_permlane32_swap)
    auto r = __builtin_amdgcn_permlane32_swap(__float_as_uint(p), __float_as_uint(p),
                                              false, false);
    return __uint_as_float(h ? r[0] : r[1]);
#else
    return __shfl_xor(p, 32);
#endif
}

// Wave-wide sum via DPP. Valid in lane 63.
__device__ __forceinline__ float dpp_reduce63(float x) {
    x += __int_as_float(__builtin_amdgcn_update_dpp(0, __float_as_int(x), 0x111, 0xf, 0xf, true));
    x += __int_as_float(__builtin_amdgcn_update_dpp(0, __float_as_int(x), 0x112, 0xf, 0xf, true));
    x += __int_as_float(__builtin_amdgcn_update_dpp(0, __float_as_int(x), 0x114, 0xf, 0xf, true));
    x += __int_as_float(__builtin_amdgcn_update_dpp(0, __float_as_int(x), 0x118, 0xf, 0xf, true));
    x += __int_as_float(__builtin_amdgcn_update_dpp(0, __float_as_int(x), 0x142, 0xf, 0xf, true));
    x += __int_as_float(__builtin_amdgcn_update_dpp(0, __float_as_int(x), 0x143, 0xf, 0xf, true));
    return x;
}

// Block-per-batch, 2-wave BARRIER-FREE producer/consumer LSTM.
// Dataflow is one-directional (wave0 -> wave1), so no per-step barrier:
//   wave0: layer1 (h1 register self-recurrence) + partialA = W_ih2_rowA . h1
//          -> ships {h1(t), partialA(t)} into a 64-slot LDS ring, bumps prog0.
//          Never waits (WAR check vs prog1 only every 32 steps).
//   wave1: W_hh2 . h2 (register self-recurrence) runs first (independent),
//          then polls prog0 (already satisfied in steady state), reads slot,
//          adds W_ih2_rowB . h1 from LDS chunks, gates, fc store (in flight).
// DS ops are in-order per wave => data-write before counter-write needs no fence
// (belt-and-braces lgkmcnt(0) kept). R8 lesson: the lockstep barrier itself was
// the floor (~60% of each step spent waiting), not the vmcnt drain.
__global__ __launch_bounds__(128, 1)
void lstm2_kernel(const float* __restrict__ x,
                  const float* __restrict__ w_ih1, const float* __restrict__ w_hh1,
                  const float* __restrict__ b_ih1, const float* __restrict__ b_hh1,
                  const float* __restrict__ w_ih2, const float* __restrict__ w_hh2,
                  const float* __restrict__ b_ih2, const float* __restrict__ b_hh2,
                  const float* __restrict__ w_fc,  const float* __restrict__ b_fc,
                  float* __restrict__ out)
{
    const int b    = blockIdx.x;
    const int tid  = threadIdx.x;
    const int wave = tid >> 6;
    const int lane = tid & 63;
    const int k    = lane & 31;
    const int h    = lane >> 5;
    const int kk   = (k < HID) ? k : (HID - 1);  // lanes k=30,31 duplicate unit 29
    const int rowA = h * 30 + kk;                // h0: i-row, h1: f-row
    const int rowB = 60 + h * 30 + kk;           // h0: g-row, h1: o-row

    __shared__ __align__(16) float ring_h1[RING][32];  // h1(t) at slot t%64 (30 used)
    __shared__ __align__(16) float ring_pA[RING][64];  // partialA(t) per lane
    __shared__ int prog[2];                            // prog0: shipped, prog1: consumed
    // init: pad words [30],[31] of every h1 slot must be 0 (never rewritten)
    for (int i = tid; i < RING; i += 128) { ring_h1[i][30] = 0.0f; ring_h1[i][31] = 0.0f; }
    if (tid == 0) { prog[0] = -1; prog[1] = -1; }
    __syncthreads();   // once, outside the loop

    volatile int* vprog0 = &prog[0];
    volatile int* vprog1 = &prog[1];

    // ---- shared-name per-wave weights (union live set ~96 regs, no spills) ----
    // wave0: wq0=whh1_rowA, wq1=whh1_rowB, wq2=wih2_rowA
    // wave1: wq0=wih2_rowB, wq1=whh2_rowA, wq2=whh2_rowB
    float wq0[32], wq1[32], wq2[32];
    float bb0 = 0.0f, bb1 = 0.0f;   // wave0: b1 rows; wave1: b2 rows
    float wxa = 0.0f, wxb = 0.0f;   // wave0 only: w_ih1 rows
    float wfck = 0.0f;              // wave1 only
    if (wave == 0) {
#pragma unroll
        for (int j = 0; j < 32; ++j) {
            wq0[j] = (j < HID) ? w_hh1[rowA * HID + j] : 0.0f;
            wq1[j] = (j < HID) ? w_hh1[rowB * HID + j] : 0.0f;
            wq2[j] = (j < HID) ? w_ih2[rowA * HID + j] : 0.0f;
        }
        bb0 = b_ih1[rowA] + b_hh1[rowA];
        bb1 = b_ih1[rowB] + b_hh1[rowB];
        wxa = w_ih1[rowA];
        wxb = w_ih1[rowB];
    } else {
#pragma unroll
        for (int j = 0; j < 32; ++j) {
            wq0[j] = (j < HID) ? w_ih2[rowB * HID + j] : 0.0f;
            wq1[j] = (j < HID) ? w_hh2[rowA * HID + j] : 0.0f;
            wq2[j] = (j < HID) ? w_hh2[rowB * HID + j] : 0.0f;
        }
        bb0 = b_ih2[rowA] + b_hh2[rowA];
        bb1 = b_ih2[rowB] + b_hh2[rowB];
        wfck = (h && k < HID) ? w_fc[k] : 0.0f;
    }
#pragma unroll
    for (int j = 0; j < 32; ++j) { pinf(wq0[j]); pinf(wq1[j]); pinf(wq2[j]); }
    pinf(bb0); pinf(bb1); pinf(wxa); pinf(wxb); pinf(wfck);
    const float bfc = __int_as_float(__builtin_amdgcn_readfirstlane(__float_as_int(b_fc[0])));

    // gate-y activation constants: h0 -> tanh (g), h1 -> sigmoid (o)
    const float cy = h ? (-L2E) : (-2.0f * L2E);
    const float my = h ? 1.0f : 2.0f;
    const float ay = h ? 0.0f : -1.0f;

    float hh  = 0.0f;   // wave0: h1[kk] (h=1 half); wave1: h2[kk]
    float cst = 0.0f;   // wave0: c1;  wave1: c2
    const float* xp   = x   + (size_t)b * TSTEPS;
    float*       outp = out + (size_t)b * TSTEPS;

    if (wave == 0) {
        // ======================= producer: layer 1 =======================
        float xv_cur = xp[lane];
        float xv_nxt = xp[64 + lane];
        for (int tt = 0; tt <= TSTEPS; ++tt) {
            // WAR guard: next 32 steps write slots (tt-1)..(tt+30), destroying
            // contents of steps (tt-65)..(tt-34) -> need prog1 >= tt-34.
            if ((tt & 31) == 0) {
                while (*vprog1 < tt - 33) __builtin_amdgcn_s_sleep(2);
                asm volatile("" ::: "memory");
            }
            const int slot = (tt - 1) & (RING - 1);
            if (tt >= 1 && h) ring_h1[slot][kk] = hh;      // ship h1(tt-1)
            float xt = 0.0f;
            if (tt < TSTEPS) {
                if ((tt & 63) == 0 && tt) {
                    xv_cur = xv_nxt;                       // loaded 64 iters ago
                    if (tt + 64 < TSTEPS) xv_nxt = xp[tt + 64 + lane];
                }
                xt = rl(xv_cur, tt & 63);
            }
            float a0 = fmaf(xt, wxa, bb0), a1 = 0.0f;      // rowA pre (i/f)
            float g0 = fmaf(xt, wxb, bb1), g1 = 0.0f;      // rowB pre (g/o)
            float p0 = 0.0f, p1 = 0.0f;                    // partialA for slot
#pragma unroll
            for (int j = 0; j < 30; j += 2) {
                const float hj0 = rl(hh, 32 + j);          // h1(tt-1)[j]
                const float hj1 = rl(hh, 33 + j);
                a0 = fmaf(wq0[j],     hj0, a0);
                g0 = fmaf(wq1[j],     hj0, g0);
                p0 = fmaf(wq2[j],     hj0, p0);
                a1 = fmaf(wq0[j + 1], hj1, a1);
                g1 = fmaf(wq1[j + 1], hj1, g1);
                p1 = fmaf(wq2[j + 1], hj1, p1);
            }
            if (tt >= 1) {
                ring_pA[slot][lane] = p0 + p1;             // partialA(tt-1)
                asm volatile("s_waitcnt lgkmcnt(0)" ::: "memory");
                if (lane == 0) *vprog0 = tt - 1;           // publish slot tt-1
            }
            if (tt < TSTEPS) {
                const float preA = a0 + a1, preB = g0 + g1;
                const float gx = frcp(1.0f + fexp2(preA * (-L2E)));           // i / f
                const float gy = fmaf(frcp(1.0f + fexp2(preB * cy)), my, ay); // g / o
                const float p  = gx * gy;                   // h0: i*g
                const float px = other_half(p, h);
                cst = fmaf(gx, cst, px);                    // h1: f*c1 + i*g
                const float tc = fmaf(2.0f, frcp(1.0f + fexp2(cst * (-2.0f * L2E))), -1.0f);
                hh = gy * tc;                               // h1(tt)[kk] in h=1 half
            }
        }
    } else {
        // ======================= consumer: layer 2 + fc =======================
        for (int s = 0; s < TSTEPS; ++s) {
            // h2 self-recurrence part first (independent of the slot)
            float dA0 = 0.0f, dA1 = 0.0f, dB0 = 0.0f, dB1 = 0.0f;
#pragma unroll
            for (int j = 0; j < 30; j += 2) {
                const float hj0 = rl(hh, 32 + j);          // h2(s-1)[j]
                const float hj1 = rl(hh, 33 + j);
                dA0 = fmaf(wq1[j],     hj0, dA0);
                dB0 = fmaf(wq2[j],     hj0, dB0);
                dA1 = fmaf(wq1[j + 1], hj1, dA1);
                dB1 = fmaf(wq2[j + 1], hj1, dB1);
            }
            // wait for slot s (steady state: already shipped)
            while (*vprog0 < s) __builtin_amdgcn_s_sleep(1);
            asm volatile("" ::: "memory");
            const int slot = s & (RING - 1);
            const v4f* hc4 = (const v4f*)ring_h1[slot];
            float e0 = 0.0f, e1 = 0.0f;                    // wih2_rowB . h1(s)
#pragma unroll
            for (int c = 0; c < 8; ++c) {
                const v4f hc = hc4[c];                     // broadcast read; pads=0
                e0 = fmaf(wq0[4 * c + 0], hc.x, e0);
                e1 = fmaf(wq0[4 * c + 1], hc.y, e1);
                e0 = fmaf(wq0[4 * c + 2], hc.z, e0);
                e1 = fmaf(wq0[4 * c + 3], hc.w, e1);
            }
            const float pA = ring_pA[slot][lane];          // wih2_rowA . h1(s)
            const float preA = (dA0 + dA1) + (pA + bb0);
            const float preB = (dB0 + dB1) + ((e0 + e1) + bb1);
            const float gx = frcp(1.0f + fexp2(preA * (-L2E)));
            const float gy = fmaf(frcp(1.0f + fexp2(preB * cy)), my, ay);
            const float p  = gx * gy;
            const float px = other_half(p, h);
            cst = fmaf(gx, cst, px);                       // c2
            const float tc = fmaf(2.0f, frcp(1.0f + fexp2(cst * (-2.0f * L2E))), -1.0f);
            hh = gy * tc;                                  // h2(s)[kk] in h=1 half
            const float sum = dpp_reduce63(wfck * hh);     // fc head
            if (lane == 63) outp[s] = sum + bfc;           // stays in flight
            if (lane == 0) *vprog1 = s;                    // after slot reads (DS in-order)
        }
    }
}

extern "C" void kernel_launch(void* const* d_in, const int* in_sizes, int n_in,
                              void* d_out, int out_size, void* d_ws, size_t ws_size,
                              hipStream_t stream)
{
    const float* x     = (const float*)d_in[0];
    const float* w_ih1 = (const float*)d_in[1];
    const float* w_hh1 = (const float*)d_in[2];
    const float* b_ih1 = (const float*)d_in[3];
    const float* b_hh1 = (const float*)d_in[4];
    const float* w_ih2 = (const float*)d_in[5];
    const float* w_hh2 = (const float*)d_in[6];
    const float* b_ih2 = (const float*)d_in[7];
    const float* b_hh2 = (const float*)d_in[8];
    const float* w_fc  = (const float*)d_in[9];
    const float* b_fc  = (const float*)d_in[10];
    float* out = (float*)d_out;

    lstm2_kernel<<<BATCH, 128, 0, stream>>>(x, w_ih1, w_hh1, b_ih1, b_hh1,
                                            w_ih2, w_hh2, b_ih2, b_hh2,
                                            w_fc, b_fc, out);
}

// Round 10
// 1157.924 us; speedup vs baseline: 1.3044x; 1.3044x over previous
//
#include <hip/hip_runtime.h>

typedef float v2f __attribute__((ext_vector_type(2)));
typedef float v4f __attribute__((ext_vector_type(4)));

#define HID 30
#define TSTEPS 2048
#define BATCH 512
#define RING 64
#define L2E 1.4426950408889634f

__device__ __forceinline__ float fexp2(float x) { return __builtin_amdgcn_exp2f(x); }
__device__ __forceinline__ float frcp(float x)  { return __builtin_amdgcn_rcpf(x); }
__device__ __forceinline__ void  pinf(float& v) { asm("" : "+v"(v)); }

// broadcast lane l of v to all lanes — VALU, result lands in SGPR
__device__ __forceinline__ float rl(float v, int l) {
    return __int_as_float(__builtin_amdgcn_readlane(__float_as_int(v), l));
}

// p from the other 32-lane half (lane ^ 32) via gfx950 VALU permlane32_swap.
__device__ __forceinline__ float other_half(float p, int h) {
#if __has_builtin(__builtin_amdgcn_permlane32_swap)
    auto r = __builtin_amdgcn_permlane32_swap(__float_as_uint(p), __float_as_uint(p),
                                              false, false);
    return __uint_as_float(h ? r[0] : r[1]);
#else
    return __shfl_xor(p, 32);
#endif
}

// Wave-wide sum via DPP. Valid in lane 63.
__device__ __forceinline__ float dpp_reduce63(float x) {
    x += __int_as_float(__builtin_amdgcn_update_dpp(0, __float_as_int(x), 0x111, 0xf, 0xf, true));
    x += __int_as_float(__builtin_amdgcn_update_dpp(0, __float_as_int(x), 0x112, 0xf, 0xf, true));
    x += __int_as_float(__builtin_amdgcn_update_dpp(0, __float_as_int(x), 0x114, 0xf, 0xf, true));
    x += __int_as_float(__builtin_amdgcn_update_dpp(0, __float_as_int(x), 0x118, 0xf, 0xf, true));
    x += __int_as_float(__builtin_amdgcn_update_dpp(0, __float_as_int(x), 0x142, 0xf, 0xf, true));
    x += __int_as_float(__builtin_amdgcn_update_dpp(0, __float_as_int(x), 0x143, 0xf, 0xf, true));
    return x;
}

// Block-per-batch, 3-wave DECOUPLED producer/consumer LSTM (no per-step barrier).
//   wave0: layer1 (h1 reg self-recurrence) -> ring_h1, publish prog[0] every 2.
//   wave1: partial W_ih2.h1 + b2 (NO recurrence) -> ring_p, publish prog[2]
//          every step, prog[1] (h1 consumed) every 8.
//   wave2: W_hh2.h2 self-recurrence + gates + fc, publish prog[3] every 8.
// 60 pinned weight floats per wave (R8-proven no-spill budget; R9's 96 spilled).
// Polls amortized x8/x32; DS pipe is in-order per wave, publishes preceded by
// lgkmcnt(0) (R9-proven protocol). Dataflow is one-directional -> each wave
// runs at its own chain speed; wall = max(wave) not sum(skews) (R8 lesson).
__global__ __launch_bounds__(192, 1)
void lstm2_kernel(const float* __restrict__ x,
                  const float* __restrict__ w_ih1, const float* __restrict__ w_hh1,
                  const float* __restrict__ b_ih1, const float* __restrict__ b_hh1,
                  const float* __restrict__ w_ih2, const float* __restrict__ w_hh2,
                  const float* __restrict__ b_ih2, const float* __restrict__ b_hh2,
                  const float* __restrict__ w_fc,  const float* __restrict__ b_fc,
                  float* __restrict__ out)
{
    const int b    = blockIdx.x;
    const int tid  = threadIdx.x;
    const int wave = tid >> 6;
    const int lane = tid & 63;
    const int k    = lane & 31;
    const int h    = lane >> 5;
    const int kk   = (k < HID) ? k : (HID - 1);  // lanes k=30,31 duplicate unit 29
    const int rowA = h * 30 + kk;                // h0: i-row, h1: f-row
    const int rowB = 60 + h * 30 + kk;           // h0: g-row, h1: o-row

    __shared__ __align__(16) float ring_h1[RING][32];   // h1(t) at slot t%64 (30 used)
    __shared__ __align__(16) float ring_p[RING][128];   // partial v2f per lane
    __shared__ int prog[4];  // 0: h1 shipped, 1: h1 consumed, 2: p shipped, 3: p consumed
    for (int i = tid; i < RING; i += 192) { ring_h1[i][30] = 0.0f; ring_h1[i][31] = 0.0f; }
    if (tid < 4) prog[tid] = -1;
    __syncthreads();   // once, outside the loop
    volatile int* vp = (volatile int*)prog;

    // ---- 60 pinned weight floats per wave (shared names across waves) ----
    // wave0: wr0/wr1 = whh1 rowA/rowB;  wave1: wih2 rowA/rowB;  wave2: whh2 rowA/rowB
    float wr0[32], wr1[32];
    float bb0 = 0.0f, bb1 = 0.0f;   // wave0: b1 rows; wave1: b2 rows
    float wxa = 0.0f, wxb = 0.0f;   // wave0 only
    float wfck = 0.0f;              // wave2 only
    if (wave == 0) {
#pragma unroll
        for (int j = 0; j < 32; ++j) {
            wr0[j] = (j < HID) ? w_hh1[rowA * HID + j] : 0.0f;
            wr1[j] = (j < HID) ? w_hh1[rowB * HID + j] : 0.0f;
        }
        bb0 = b_ih1[rowA] + b_hh1[rowA];
        bb1 = b_ih1[rowB] + b_hh1[rowB];
        wxa = w_ih1[rowA];
        wxb = w_ih1[rowB];
    } else if (wave == 1) {
#pragma unroll
        for (int j = 0; j < 32; ++j) {
            wr0[j] = (j < HID) ? w_ih2[rowA * HID + j] : 0.0f;
            wr1[j] = (j < HID) ? w_ih2[rowB * HID + j] : 0.0f;
        }
        bb0 = b_ih2[rowA] + b_hh2[rowA];
        bb1 = b_ih2[rowB] + b_hh2[rowB];
    } else {
#pragma unroll
        for (int j = 0; j < 32; ++j) {
            wr0[j] = (j < HID) ? w_hh2[rowA * HID + j] : 0.0f;
            wr1[j] = (j < HID) ? w_hh2[rowB * HID + j] : 0.0f;
        }
        wfck = (h && k < HID) ? w_fc[k] : 0.0f;
    }
#pragma unroll
    for (int j = 0; j < 32; ++j) { pinf(wr0[j]); pinf(wr1[j]); }
    pinf(bb0); pinf(bb1); pinf(wxa); pinf(wxb); pinf(wfck);
    const float bfc = __int_as_float(__builtin_amdgcn_readfirstlane(__float_as_int(b_fc[0])));

    // gate-y activation constants: h0 -> tanh (g), h1 -> sigmoid (o)
    const float cy = h ? (-L2E) : (-2.0f * L2E);
    const float my = h ? 1.0f : 2.0f;
    const float ay = h ? 0.0f : -1.0f;

    float hh  = 0.0f;   // wave0: h1[kk] (h=1 half); wave2: h2[kk]
    float cst = 0.0f;   // wave0: c1;  wave2: c2
    const float* xp   = x   + (size_t)b * TSTEPS;
    float*       outp = out + (size_t)b * TSTEPS;

    if (wave == 0) {
        // =================== free-running producer: layer 1 ===================
        float xv_cur = xp[lane];
        float xv_nxt = xp[64 + lane];
        for (int tt = 0; tt < TSTEPS; ++tt) {
            if ((tt & 31) == 0) {   // WAR: slots tt..tt+31 overwrite h1(tt-64..tt-33)
                while (vp[1] < tt - 33) __builtin_amdgcn_s_sleep(2);
                asm volatile("" ::: "memory");
            }
            if ((tt & 63) == 0 && tt) {
                xv_cur = xv_nxt;                           // loaded 64 iters ago
                if (tt + 64 < TSTEPS) xv_nxt = xp[tt + 64 + lane];
            }
            const float xt = rl(xv_cur, tt & 63);
            float a0 = fmaf(xt, wxa, bb0), a1 = 0.0f;      // rowA pre (i/f)
            float g0 = fmaf(xt, wxb, bb1), g1 = 0.0f;      // rowB pre (g/o)
#pragma unroll
            for (int j = 0; j < 30; j += 2) {
                const float hj0 = rl(hh, 32 + j);          // h1(tt-1)[j]
                const float hj1 = rl(hh, 33 + j);
                a0 = fmaf(wr0[j],     hj0, a0);
                g0 = fmaf(wr1[j],     hj0, g0);
                a1 = fmaf(wr0[j + 1], hj1, a1);
                g1 = fmaf(wr1[j + 1], hj1, g1);
            }
            const float preA = a0 + a1, preB = g0 + g1;
            const float gx = frcp(1.0f + fexp2(preA * (-L2E)));           // i / f
            const float gy = fmaf(frcp(1.0f + fexp2(preB * cy)), my, ay); // g / o
            const float p  = gx * gy;
            const float px = other_half(p, h);
            cst = fmaf(gx, cst, px);                       // c1
            const float tc = fmaf(2.0f, frcp(1.0f + fexp2(cst * (-2.0f * L2E))), -1.0f);
            hh = gy * tc;                                  // h1(tt)[kk] in h=1 half
            if (h) ring_h1[tt & (RING - 1)][kk] = hh;      // ship h1(tt)
            if (tt & 1) {                                  // publish every 2 steps
                asm volatile("s_waitcnt lgkmcnt(0)" ::: "memory");
                if (lane == 0) vp[0] = tt;
            }
        }
    } else if (wave == 1) {
        // ============ throughput stage (no recurrence): W_ih2.h1 + b2 ============
        for (int s = 0; s < TSTEPS; ++s) {
            if ((s & 7) == 0) {
                while (vp[0] < s + 7) __builtin_amdgcn_s_sleep(1);   // h1 avail
                while (vp[3] < s - 57) __builtin_amdgcn_s_sleep(1);  // WAR on ring_p
                asm volatile("" ::: "memory");
            }
            const v4f* hc4 = (const v4f*)ring_h1[s & (RING - 1)];
            float e0 = bb0, e1 = 0.0f;                     // rowA partial
            float f0 = bb1, f1 = 0.0f;                     // rowB partial
#pragma unroll
            for (int c = 0; c < 8; ++c) {
                const v4f hc = hc4[c];                     // broadcast read; pads=0
                e0 = fmaf(wr0[4 * c + 0], hc.x, e0);
                f0 = fmaf(wr1[4 * c + 0], hc.x, f0);
                e1 = fmaf(wr0[4 * c + 1], hc.y, e1);
                f1 = fmaf(wr1[4 * c + 1], hc.y, f1);
                e0 = fmaf(wr0[4 * c + 2], hc.z, e0);
                f0 = fmaf(wr1[4 * c + 2], hc.z, f0);
                e1 = fmaf(wr0[4 * c + 3], hc.w, e1);
                f1 = fmaf(wr1[4 * c + 3], hc.w, f1);
            }
            v2f pr;
            pr.x = e0 + e1;
            pr.y = f0 + f1;
            ((v2f*)ring_p[s & (RING - 1)])[lane] = pr;
            asm volatile("s_waitcnt lgkmcnt(0)" ::: "memory");
            if (lane == 0) {
                vp[2] = s;                                 // partial shipped
                if ((s & 7) == 7) vp[1] = s;               // h1 consumed (reads precede in DS order)
            }
        }
    } else {
        // ============ consumer: W_hh2.h2 self-recurrence + gates + fc ============
        for (int s = 0; s < TSTEPS; ++s) {
            if ((s & 7) == 0) {
                while (vp[2] < s + 7) __builtin_amdgcn_s_sleep(1);   // partials avail
                asm volatile("" ::: "memory");
            }
            const v2f part = ((const v2f*)ring_p[s & (RING - 1)])[lane]; // hidden under matvec
            float dA0 = 0.0f, dA1 = 0.0f, dB0 = 0.0f, dB1 = 0.0f;
#pragma unroll
            for (int j = 0; j < 30; j += 2) {
                const float hj0 = rl(hh, 32 + j);          // h2(s-1)[j]
                const float hj1 = rl(hh, 33 + j);
                dA0 = fmaf(wr0[j],     hj0, dA0);
                dB0 = fmaf(wr1[j],     hj0, dB0);
                dA1 = fmaf(wr0[j + 1], hj1, dA1);
                dB1 = fmaf(wr1[j + 1], hj1, dB1);
            }
            const float preA = (dA0 + dA1) + part.x;
            const float preB = (dB0 + dB1) + part.y;
            const float gx = frcp(1.0f + fexp2(preA * (-L2E)));
            const float gy = fmaf(frcp(1.0f + fexp2(preB * cy)), my, ay);
            const float p  = gx * gy;
            const float px = other_half(p, h);
            cst = fmaf(gx, cst, px);                       // c2
            const float tc = fmaf(2.0f, frcp(1.0f + fexp2(cst * (-2.0f * L2E))), -1.0f);
            hh = gy * tc;                                  // h2(s)[kk] in h=1 half
            const float sum = dpp_reduce63(wfck * hh);     // fc head
            if (lane == 63) outp[s] = sum + bfc;           // store stays in flight
            if ((s & 7) == 7) {                            // publish consumption every 8
                asm volatile("s_waitcnt lgkmcnt(0)" ::: "memory");
                if (lane == 0) vp[3] = s;
            }
        }
    }
}

extern "C" void kernel_launch(void* const* d_in, const int* in_sizes, int n_in,
                              void* d_out, int out_size, void* d_ws, size_t ws_size,
                              hipStream_t stream)
{
    const float* x     = (const float*)d_in[0];
    const float* w_ih1 = (const float*)d_in[1];
    const float* w_hh1 = (const float*)d_in[2];
    const float* b_ih1 = (const float*)d_in[3];
    const float* b_hh1 = (const float*)d_in[4];
    const float* w_ih2 = (const float*)d_in[5];
    const float* w_hh2 = (const float*)d_in[6];
    const float* b_ih2 = (const float*)d_in[7];
    const float* b_hh2 = (const float*)d_in[8];
    const float* w_fc  = (const float*)d_in[9];
    const float* b_fc  = (const float*)d_in[10];
    float* out = (float*)d_out;

    lstm2_kernel<<<BATCH, 192, 0, stream>>>(x, w_ih1, w_hh1, b_ih1, b_hh1,
                                            w_ih2, w_hh2, b_ih2, b_hh2,
                                            w_fc, b_fc, out);
}